// Round 1
// 666.784 us; speedup vs baseline: 1.0810x; 1.0810x over previous
//
#include <hip/hip_runtime.h>

#define N_NODES 10000
#define F_IN    256
#define H1      128
#define H2      64
#define NEDGE   320000
#define M_TOT   (NEDGE + N_NODES)

typedef __attribute__((ext_vector_type(8))) short          s16v8;  // 8 bf16 (4 VGPRs)
typedef __attribute__((ext_vector_type(8))) unsigned short u16v8;
typedef __attribute__((ext_vector_type(4))) float          f32v4;

// ---------------------------------------------------------------- graph prep
// NOTE: harness passes integer inputs as int32 (edge_index int64 -> int32).

__global__ void k_init(float* deg, int* cnt) {
    int i = blockIdx.x * blockDim.x + threadIdx.x;
    if (i < N_NODES) { deg[i] = 1.0f; cnt[i] = 1; }   // self-loop weight 1, count 1
}

__global__ void k_count(const int* __restrict__ ei, const float* __restrict__ w,
                        float* deg, int* cnt) {
    int e = blockIdx.x * blockDim.x + threadIdx.x;
    if (e < NEDGE) {
        int c = ei[NEDGE + e];                // col
        atomicAdd(&deg[c], w[e]);
        atomicAdd(&cnt[c], 1);
    }
}

// exclusive scan of cnt[0..N) -> ptr, one block of 1024 threads, 10 items each
__global__ void k_scan(const int* __restrict__ cnt, int* __restrict__ ptr,
                       int* __restrict__ cur) {
    __shared__ int part[1024];
    int t = threadIdx.x;
    int base = t * 10;
    int local[10];
    int s = 0;
#pragma unroll
    for (int j = 0; j < 10; j++) {
        int idx = base + j;
        int v = (idx < N_NODES) ? cnt[idx] : 0;
        local[j] = s;
        s += v;
    }
    part[t] = s;
    __syncthreads();
    for (int off = 1; off < 1024; off <<= 1) {
        int v = (t >= off) ? part[t - off] : 0;
        __syncthreads();
        part[t] += v;
        __syncthreads();
    }
    int excl = t ? part[t - 1] : 0;
#pragma unroll
    for (int j = 0; j < 10; j++) {
        int idx = base + j;
        if (idx < N_NODES) {
            int p = excl + local[j];
            ptr[idx] = p;
            cur[idx] = p;
        }
    }
    if (t == 1023) ptr[N_NODES] = part[1023];
}

// scatter edges (+self loops) into CSR-by-col; rsqrt folded in (was k_rsqrt)
__global__ void k_scatter(const int* __restrict__ ei, const float* __restrict__ w,
                          const float* __restrict__ deg, int* cur,
                          int* __restrict__ src, float* __restrict__ wgt) {
    int t = blockIdx.x * blockDim.x + threadIdx.x;
    if (t >= M_TOT) return;
    int r, c; float nw;
    if (t < NEDGE) {
        r = ei[t];
        c = ei[NEDGE + t];
        nw = rsqrtf(deg[r]) * w[t] * rsqrtf(deg[c]);   // same values as dis[r]*w*dis[c]
    } else {
        r = c = t - NEDGE;
        float d = rsqrtf(deg[r]);
        nw = d * d;
    }
    int pos = atomicAdd(&cur[c], 1);
    src[pos] = r;
    wgt[pos] = nw;
}

// ---------------------------------------------------------------- dense GEMMs

// hw = x @ W1   [10000,256]x[256,128]; 8 rows/block, 128 threads (1 col each)
// Inner loop vectorized over k: 2 broadcast ds_read_b128 per 4 k-steps instead
// of 8 scalar b32 per k-step (LDS-pipe was the bottleneck).
__global__ __launch_bounds__(128) void k_gemm1(const float* __restrict__ x,
                                               const float* __restrict__ W1,
                                               float* __restrict__ hw) {
    __shared__ float xs[8 * F_IN];
    int i0 = blockIdx.x * 8;
    int t = threadIdx.x;
    const float4* xsrc = (const float4*)(x + (size_t)i0 * F_IN);
    float4* xd = (float4*)xs;
#pragma unroll
    for (int j = 0; j < 4; j++) xd[t + j * 128] = xsrc[t + j * 128];
    __syncthreads();
    float acc[8] = {0, 0, 0, 0, 0, 0, 0, 0};
    for (int k = 0; k < F_IN; k += 4) {
        float w0 = W1[(k + 0) * H1 + t];
        float w1 = W1[(k + 1) * H1 + t];
        float w2 = W1[(k + 2) * H1 + t];
        float w3 = W1[(k + 3) * H1 + t];
#pragma unroll
        for (int r = 0; r < 8; r++) {
            float4 xv = *(const float4*)&xs[r * F_IN + k];   // wave-uniform broadcast
            acc[r] += xv.x * w0 + xv.y * w1 + xv.z * w2 + xv.w * w3;
        }
    }
#pragma unroll
    for (int r = 0; r < 8; r++) hw[(size_t)(i0 + r) * H1 + t] = acc[r];
}

// t2 = h1 @ W2, t3 = h1 @ W3  [10000,128]x[128,64] twice; wave0->W2, wave1->W3
__global__ __launch_bounds__(128) void k_gemm23(const float* __restrict__ h1,
                                                const float* __restrict__ W2,
                                                const float* __restrict__ W3,
                                                float* __restrict__ t2,
                                                float* __restrict__ t3) {
    __shared__ float hs[8 * H1];
    int i0 = blockIdx.x * 8;
    int t = threadIdx.x;
    const float4* hsrc = (const float4*)(h1 + (size_t)i0 * H1);
    float4* hd = (float4*)hs;
#pragma unroll
    for (int j = 0; j < 2; j++) hd[t + j * 128] = hsrc[t + j * 128];
    __syncthreads();
    int f = t & 63;
    int sel = t >> 6;                      // wave-uniform
    const float* W = sel ? W3 : W2;
    float acc[8] = {0, 0, 0, 0, 0, 0, 0, 0};
    for (int k = 0; k < H1; k += 4) {
        float w0 = W[(k + 0) * H2 + f];
        float w1 = W[(k + 1) * H2 + f];
        float w2 = W[(k + 2) * H2 + f];
        float w3 = W[(k + 3) * H2 + f];
#pragma unroll
        for (int r = 0; r < 8; r++) {
            float4 hv = *(const float4*)&hs[r * H1 + k];     // wave-uniform broadcast
            acc[r] += hv.x * w0 + hv.y * w1 + hv.z * w2 + hv.w * w3;
        }
    }
    float* o = sel ? t3 : t2;
#pragma unroll
    for (int r = 0; r < 8; r++) o[(size_t)(i0 + r) * H2 + f] = acc[r];
}

// ---------------------------------------------------------------- aggregations

// h1 = relu(segsum(norm * hw[row]) + b1)   one block per node, 128 feats
__global__ __launch_bounds__(128) void k_agg1(const int* __restrict__ ptr,
                                              const int* __restrict__ src,
                                              const float* __restrict__ wgt,
                                              const float* __restrict__ hw,
                                              const float* __restrict__ b1,
                                              float* __restrict__ h1) {
    int i = blockIdx.x;
    int f = threadIdx.x;
    int jb = ptr[i], je = ptr[i + 1];
    float acc = b1[f];
    for (int j = jb; j < je; j++)
        acc += wgt[j] * hw[(size_t)src[j] * H1 + f];
    h1[(size_t)i * H1 + f] = fmaxf(acc, 0.0f);
}

// mu = segsum(norm * t2[row]) + b2 ; logvar = ... t3/b3.  wave0->mu, wave1->logvar
__global__ __launch_bounds__(128) void k_agg2(const int* __restrict__ ptr,
                                              const int* __restrict__ src,
                                              const float* __restrict__ wgt,
                                              const float* __restrict__ t2,
                                              const float* __restrict__ t3,
                                              const float* __restrict__ b2,
                                              const float* __restrict__ b3,
                                              float* __restrict__ mu,
                                              float* __restrict__ lv) {
    int i = blockIdx.x;
    int t = threadIdx.x;
    int f = t & 63;
    int sel = t >> 6;                      // wave-uniform
    const float* tin = sel ? t3 : t2;
    float acc = sel ? b3[f] : b2[f];
    int jb = ptr[i], je = ptr[i + 1];
    for (int j = jb; j < je; j++)
        acc += wgt[j] * tin[(size_t)src[j] * H2 + f];
    float* o = sel ? lv : mu;
    o[(size_t)i * H2 + f] = acc;
}

// ---------------------------------------------------------------- adj = z z^T
//
// MFMA version. z (=mu) is split exactly on the fly into 3 bf16 planes
// (z = h + m + l, truncation; residual <= 2^-24 |z|), and adj is computed as
// the 6 significant cross products hh+hm+mh+hl+lh+mm on v_mfma_f32_16x16x32_bf16.
// Dropped terms (ml, lm, ll) are <= ~2^-26 relative -> precision >= fp32 path.
//
// 128x128 tile / block, 256 thr = 4 waves, each wave one 64x64 quadrant
// (4x4 frags of 16x16, f32v4 acc each). K=64 done as two 32-k stages so the
// 6 LDS planes fit in 48 KB ([128 rows][32 k] bf16 per plane, 16B-chunk
// XOR-swizzle c ^= (row>>1)&3 -> frag reads ~2-way conflict = free).
// Stage-1 global loads are issued before the stage-0 MFMAs (latency overlap).
//
// MFMA frag layouts (guide §3, m89-verified C/D):
//   A lane l: row = l&15, k = 8*(l>>4)+q   (8 contiguous bf16 = 1 ds_read_b128)
//   B lane l: col = l&15, k = 8*(l>>4)+q   (same pattern since B = z^T)
//   D lane l: col = l&15, row = 4*(l>>4)+reg
__global__ __launch_bounds__(256, 1) void k_adj(const float* __restrict__ z,
                                                float* __restrict__ adj) {
    __shared__ __align__(16) unsigned short Ap[3][128 * 32];
    __shared__ __align__(16) unsigned short Bp[3][128 * 32];
    int tid = threadIdx.x;
    int rowBase = blockIdx.y * 128, colBase = blockIdx.x * 128;

    int lane = tid & 63;
    int wv   = tid >> 6;
    int wr = (wv >> 1) * 64;               // wave's output quadrant
    int wc = (wv & 1) * 64;
    int lrow = lane & 15;
    int lk   = lane >> 4;                  // k-chunk within 32-k stage

    // staging role: threads 0..127 -> A row (tid), 128..255 -> B row (tid-128)
    int sr   = tid & 127;
    int isB  = tid >> 7;
    int gbase = (isB ? colBase : rowBase) + sr;
    bool ok = gbase < N_NODES;
    const float* srcp = z + (size_t)gbase * 64;
    unsigned short* P0 = isB ? Bp[0] : Ap[0];
    unsigned short* P1 = isB ? Bp[1] : Ap[1];
    unsigned short* P2 = isB ? Bp[2] : Ap[2];

    auto stage = [&](int s) {
#pragma unroll
        for (int g = 0; g < 4; g++) {      // 4 chunks of 8 k per 32-k stage
            float v[8];
            if (ok) {
                float4 a = *(const float4*)(srcp + s * 32 + g * 8);
                float4 b = *(const float4*)(srcp + s * 32 + g * 8 + 4);
                v[0] = a.x; v[1] = a.y; v[2] = a.z; v[3] = a.w;
                v[4] = b.x; v[5] = b.y; v[6] = b.z; v[7] = b.w;
            } else {
#pragma unroll
                for (int q = 0; q < 8; q++) v[q] = 0.0f;
            }
            u16v8 hv, mv, lv8;
#pragma unroll
            for (int q = 0; q < 8; q++) {
                float xv = v[q];
                unsigned hu = __float_as_uint(xv) & 0xffff0000u;       // h = trunc bf16
                float r1 = xv - __uint_as_float(hu);
                unsigned mu2 = __float_as_uint(r1) & 0xffff0000u;      // m
                float r2 = r1 - __uint_as_float(mu2);
                unsigned lu = __float_as_uint(r2) & 0xffff0000u;       // l
                hv[q]  = (unsigned short)(hu >> 16);
                mv[q]  = (unsigned short)(mu2 >> 16);
                lv8[q] = (unsigned short)(lu >> 16);
            }
            int c = g ^ ((sr >> 1) & 3);   // 16B-chunk swizzle
            int idx = sr * 32 + c * 8;
            *reinterpret_cast<u16v8*>(P0 + idx) = hv;
            *reinterpret_cast<u16v8*>(P1 + idx) = mv;
            *reinterpret_cast<u16v8*>(P2 + idx) = lv8;
        }
    };

    f32v4 acc[4][4];
#pragma unroll
    for (int i = 0; i < 4; i++)
#pragma unroll
        for (int j = 0; j < 4; j++) acc[i][j] = (f32v4)0.0f;

    s16v8 a0[4], a1[4], a2[4], b0[4], b1[4], b2[4];

#define LOADFRAGS()                                                        \
    {                                                                      \
        _Pragma("unroll")                                                  \
        for (int fq = 0; fq < 4; fq++) {                                   \
            int ra = wr + fq * 16 + lrow;                                  \
            int ca = lk ^ ((ra >> 1) & 3);                                 \
            int ia = ra * 32 + ca * 8;                                     \
            a0[fq] = *reinterpret_cast<const s16v8*>(&Ap[0][ia]);          \
            a1[fq] = *reinterpret_cast<const s16v8*>(&Ap[1][ia]);          \
            a2[fq] = *reinterpret_cast<const s16v8*>(&Ap[2][ia]);          \
            int rb = wc + fq * 16 + lrow;                                  \
            int cb = lk ^ ((rb >> 1) & 3);                                 \
            int ib = rb * 32 + cb * 8;                                     \
            b0[fq] = *reinterpret_cast<const s16v8*>(&Bp[0][ib]);          \
            b1[fq] = *reinterpret_cast<const s16v8*>(&Bp[1][ib]);          \
            b2[fq] = *reinterpret_cast<const s16v8*>(&Bp[2][ib]);          \
        }                                                                  \
    }

#define MFMAS()                                                            \
    {                                                                      \
        _Pragma("unroll")                                                  \
        for (int i = 0; i < 4; i++) {                                      \
            _Pragma("unroll")                                              \
            for (int j = 0; j < 4; j++) {                                  \
                f32v4 c = acc[i][j];                                       \
                c = __builtin_amdgcn_mfma_f32_16x16x32_bf16(a0[i], b0[j], c, 0, 0, 0); \
                c = __builtin_amdgcn_mfma_f32_16x16x32_bf16(a0[i], b1[j], c, 0, 0, 0); \
                c = __builtin_amdgcn_mfma_f32_16x16x32_bf16(a1[i], b0[j], c, 0, 0, 0); \
                c = __builtin_amdgcn_mfma_f32_16x16x32_bf16(a0[i], b2[j], c, 0, 0, 0); \
                c = __builtin_amdgcn_mfma_f32_16x16x32_bf16(a2[i], b0[j], c, 0, 0, 0); \
                c = __builtin_amdgcn_mfma_f32_16x16x32_bf16(a1[i], b1[j], c, 0, 0, 0); \
                acc[i][j] = c;                                             \
            }                                                              \
        }                                                                  \
    }

    stage(0);
    __syncthreads();
    LOADFRAGS();                // k-stage 0 frags -> regs
    __syncthreads();            // everyone done reading stage-0 LDS
    stage(1);                   // global loads overlap with MFMAs below
    MFMAS();                    // k 0..31
    __syncthreads();            // stage-1 writes visible
    LOADFRAGS();                // k-stage 1 frags
    MFMAS();                    // k 32..63

#undef LOADFRAGS
#undef MFMAS

#pragma unroll
    for (int i = 0; i < 4; i++) {
        int r0 = rowBase + wr + i * 16 + lk * 4;
#pragma unroll
        for (int j = 0; j < 4; j++) {
            int cg = colBase + wc + j * 16 + lrow;
            if (cg < N_NODES) {
#pragma unroll
                for (int v = 0; v < 4; v++) {
                    int rg = r0 + v;
                    if (rg < N_NODES)
                        adj[(size_t)rg * N_NODES + cg] = acc[i][j][v];
                }
            }
        }
    }
}

// ---------------------------------------------------------------- launch

extern "C" void kernel_launch(void* const* d_in, const int* in_sizes, int n_in,
                              void* d_out, int out_size, void* d_ws, size_t ws_size,
                              hipStream_t stream) {
    const float* x  = (const float*)d_in[0];
    const int*   ei = (const int*)d_in[1];      // harness passes ints as int32
    const float* w  = (const float*)d_in[2];
    const float* W1 = (const float*)d_in[3];
    const float* b1 = (const float*)d_in[4];
    const float* W2 = (const float*)d_in[5];
    const float* b2 = (const float*)d_in[6];
    const float* W3 = (const float*)d_in[7];
    const float* b3 = (const float*)d_in[8];

    float* out = (float*)d_out;
    float* adj = out;
    float* mu  = out + (size_t)N_NODES * N_NODES;
    float* lv  = mu + (size_t)N_NODES * H2;

    // Scratch lives in the tail of the adj region of d_out (offset 320 MB of
    // the 400 MB adj block). It is fully dead before k_adj overwrites it
    // (k_adj reads only mu, which is outside the adj region), and every
    // scratch array is written before it is read on every call.
    float* ws  = out + 80000000;
    float* deg = ws;                       // 10240 floats
    int*   cnt = (int*)(ws + 10240);       // 10240
    int*   ptr = (int*)(ws + 20480);       // 10240 (10001 used)
    int*   cur = (int*)(ws + 30720);       // 10240
    int*   src = (int*)(ws + 40960);       // 330240
    float* wgt = ws + 371200;              // 330240
    float* hw  = ws + 701440;              // 1,280,000
    float* h1  = ws + 1981440;             // 1,280,000
    float* t2  = ws + 3261440;             // 640,000
    float* t3  = ws + 3901440;             // 640,000  (ends at ws+4,541,440)

    hipLaunchKernelGGL(k_init,    dim3((N_NODES + 255) / 256), dim3(256), 0, stream, deg, cnt);
    hipLaunchKernelGGL(k_count,   dim3((NEDGE + 255) / 256),   dim3(256), 0, stream, ei, w, deg, cnt);
    hipLaunchKernelGGL(k_scan,    dim3(1), dim3(1024), 0, stream, cnt, ptr, cur);
    hipLaunchKernelGGL(k_scatter, dim3((M_TOT + 255) / 256),   dim3(256), 0, stream, ei, w, deg, cur, src, wgt);
    hipLaunchKernelGGL(k_gemm1,   dim3(N_NODES / 8),  dim3(128), 0, stream, x, W1, hw);
    hipLaunchKernelGGL(k_agg1,    dim3(N_NODES),      dim3(128), 0, stream, ptr, src, wgt, hw, b1, h1);
    hipLaunchKernelGGL(k_gemm23,  dim3(N_NODES / 8),  dim3(128), 0, stream, h1, W2, W3, t2, t3);
    hipLaunchKernelGGL(k_agg2,    dim3(N_NODES),      dim3(128), 0, stream, ptr, src, wgt, t2, t3, b2, b3, mu, lv);

    dim3 g((N_NODES + 127) / 128, (N_NODES + 127) / 128);
    hipLaunchKernelGGL(k_adj, g, dim3(256), 0, stream, mu, adj);
}